// Round 14
// baseline (761.712 us; speedup 1.0000x reference)
//
#include <hip/hip_runtime.h>
#include <hip/hip_bf16.h>

using u16 = unsigned short;
using u32 = unsigned int;

typedef __bf16 bf16x8 __attribute__((ext_vector_type(8)));
typedef float  f32x4  __attribute__((ext_vector_type(4)));
typedef u32    u32x4  __attribute__((ext_vector_type(4)));
typedef u16    u16x8  __attribute__((ext_vector_type(8)));
typedef int    i32x4  __attribute__((ext_vector_type(4)));

__device__ __forceinline__ float bflo(u32 u){ union { u32 u; float f; } c; c.u = u << 16;          return c.f; }
__device__ __forceinline__ float bfhi(u32 u){ union { u32 u; float f; } c; c.u = u & 0xffff0000u;  return c.f; }
__device__ __forceinline__ u16  f2bf(float f){
  union { float f; u32 u; } c; c.f = f;
  u32 u = c.u;
  return (u16)((u + 0x7fffu + ((u >> 16) & 1u)) >> 16); // RNE
}

__device__ __forceinline__ void gload_lds16(const void* g, void* l){
  __builtin_amdgcn_global_load_lds(
      (const __attribute__((address_space(1))) void*)g,
      (__attribute__((address_space(3))) void*)l, 16, 0, 0);
}

// ---------------- fused prep P1: count_deg (vec4) || convert_w (tiled transpose) ----------------

__global__ __launch_bounds__(256) void prep1_kernel(const int* __restrict__ dst, int E, int CB,
                                                    int* __restrict__ cnt,
                                                    const float* __restrict__ W,
                                                    u16* __restrict__ Wt){
  if ((int)blockIdx.x < CB){
    int i4 = (blockIdx.x * 256 + threadIdx.x) * 4;
    if (i4 + 3 < E){
      i32x4 d = *(const i32x4*)(dst + i4);
      atomicAdd(&cnt[d[0]], 1); atomicAdd(&cnt[d[1]], 1);
      atomicAdd(&cnt[d[2]], 1); atomicAdd(&cnt[d[3]], 1);
    } else {
      for (int i = i4; i < E; ++i) atomicAdd(&cnt[dst[i]], 1);
    }
    return;
  }
  // ---- W transpose tile: Wt[l][n][k] = bf16(W[l][k][n]) ----
  __shared__ u16 tile[64][72];
  const int tix = blockIdx.x - CB;        // 0 .. L*64-1
  const int l   = tix >> 6;
  const int kt  = ((tix >> 3) & 7) << 6;  // k tile base
  const int nt  = (tix & 7) << 6;         // n tile base
  const int tid = threadIdx.x;
  const int ty  = tid >> 4;               // 0..15
  const int tx  = tid & 15;               // 0..15 (4 floats each)
  const float* Wl = W + ((size_t)l << 18);
  #pragma unroll
  for (int q = 0; q < 4; ++q){
    const int row = (q << 4) + ty;        // k within tile
    f32x4 v = *(const f32x4*)(Wl + (((size_t)(kt + row)) << 9) + nt + (tx << 2));
    #pragma unroll
    for (int j = 0; j < 4; ++j) tile[(tx << 2) + j][row] = f2bf(v[j]);
  }
  __syncthreads();
  u16* Wtl = Wt + ((size_t)l << 18);
  #pragma unroll
  for (int rep = 0; rep < 2; ++rep){
    const int idx  = (rep << 8) + tid;    // 0..511
    const int nrow = idx >> 3;            // 0..63
    const int ch   = idx & 7;             // 8-u16 chunk
    u16x8 o;
    #pragma unroll
    for (int j = 0; j < 8; ++j) o[j] = tile[nrow][(ch << 3) + j];
    *(u16x8*)(Wtl + (((size_t)(nt + nrow)) << 9) + kt + (ch << 3)) = o;
  }
}

// ---------------- scan chain ----------------

__global__ void scan1_kernel(const int* __restrict__ cnt, int n,
                             int* __restrict__ excl, int* __restrict__ bsums){
  __shared__ int sd[1024];
  const int tid = threadIdx.x;
  const int i = blockIdx.x * 1024 + tid;
  int v = 0;
  if (i < n) v = (cnt[i] + 1 + 7) & ~7;   // +1 self edge, pad to multiple of 8 (>= 8)
  sd[tid] = v;
  __syncthreads();
  for (int s = 1; s < 1024; s <<= 1){
    int t = (tid >= s) ? sd[tid - s] : 0;
    __syncthreads();
    sd[tid] += t;
    __syncthreads();
  }
  if (i < n) excl[i] = sd[tid] - v;
  if (tid == 1023) bsums[blockIdx.x] = sd[tid];
}

__global__ void scan2_kernel(int* __restrict__ bsums, int nb){
  __shared__ int sd[256];
  const int tid = threadIdx.x;
  int v = (tid < nb) ? bsums[tid] : 0;
  sd[tid] = v;
  __syncthreads();
  for (int s = 1; s < 256; s <<= 1){
    int t = (tid >= s) ? sd[tid - s] : 0;
    __syncthreads();
    sd[tid] += t;
    __syncthreads();
  }
  if (tid < nb) bsums[tid] = sd[tid] - v;
  if (tid == nb - 1) bsums[nb] = sd[tid];
}

__global__ void finalize_kernel(int* __restrict__ rowptr, int* __restrict__ cursor,
                                const int* __restrict__ bsums, int nb,
                                const int* __restrict__ cnt,
                                float* __restrict__ dis, int n){
  int i = blockIdx.x * blockDim.x + threadIdx.x;
  if (i < n){
    int r = rowptr[i] + bsums[i >> 10];
    rowptr[i] = r;
    cursor[i] = r;
    dis[i] = rsqrtf((float)(cnt[i] + 1)); // +1 self loop
  }
  if (i == 0){
    rowptr[n] = bsums[nb];
    dis[n] = 0.f;                          // sentinel node
  }
}

// ---------------- fused prep P3: convert_x || fill_csr || pad_fill(+self edge) ----------------

__global__ __launch_bounds__(256) void prep3_kernel(const float* __restrict__ x,
                                                    const float* __restrict__ dis,
                                                    u32* __restrict__ xb,
                                                    int n_real, int n_tot, int XB,
                                                    const int* __restrict__ src,
                                                    const int* __restrict__ dst,
                                                    int E, int FB,
                                                    int* __restrict__ cursor,
                                                    const int* __restrict__ rowptr,
                                                    const int* __restrict__ cnt,
                                                    int N,
                                                    u16* __restrict__ col){
  const int b = blockIdx.x;
  if (b < XB){
    int i8 = (b * 256 + threadIdx.x) * 8;
    if (i8 >= n_tot) return;
    u32 q0, q1, q2, q3;
    if (i8 < n_real){
      const float dv = dis[i8 >> 9];
      const f32x4* xp = (const f32x4*)(x + i8);
      f32x4 a = xp[0], v = xp[1];
      q0 = ((u32)f2bf(dv * a[1]) << 16) | f2bf(dv * a[0]);
      q1 = ((u32)f2bf(dv * a[3]) << 16) | f2bf(dv * a[2]);
      q2 = ((u32)f2bf(dv * v[1]) << 16) | f2bf(dv * v[0]);
      q3 = ((u32)f2bf(dv * v[3]) << 16) | f2bf(dv * v[2]);
    } else {
      q0 = q1 = q2 = q3 = 0u;  // pad rows (incl. sentinel N) stay zero
    }
    u32x4 q = {q0, q1, q2, q3};
    *(u32x4*)(xb + (i8 >> 1)) = q;
  } else if (b < XB + FB){
    int i = (b - XB) * 256 + threadIdx.x;
    if (i < E){
      int d = dst[i];
      int p = atomicAdd(&cursor[d], 1);
      col[p] = (u16)src[i];
    }
  } else {
    int v = (b - XB - FB) * 256 + threadIdx.x;
    if (v < N){
      int p = rowptr[v] + cnt[v];
      col[p++] = (u16)v;                   // self edge: dis[v]*xs[v] == dv^2*x[v]
      const int p1 = rowptr[v + 1];
      for (; p < p1; ++p) col[p] = (u16)N; // sentinel padding (xs[N]=0)
    }
    if (v == 0){
      int t = rowptr[N];
      for (int j = 0; j < 32; ++j) col[t + j] = (u16)N;
    }
  }
}

// ---------------- aggregation: XCD feature-sliced, one wave per (node, slice-of-8) ----------------
// block b: slice f = b&7 (-> XCD b&7), node group = b>>3; 4 waves = 4 nodes.
// Wave lanes: edge-slot eg = lane>>3 (8 edges/chunk), 16B piece = lane&7 (128B slice).
// One gather instr = 8 edges x 128B = 16 lines (same as full-row, 8x fewer instrs).
// agg[v][slice] = dis[v] * sum_e xs[col[e]][slice]; self edge folded into CSR.
// Wave-uniform m -> uniform branches; 3-deep in-list pipeline; shfl_xor butterfly reduce.

#define ACCQ(q) \
  a0 += bflo((q)[0]); a1 += bfhi((q)[0]); a2 += bflo((q)[1]); a3 += bfhi((q)[1]); \
  a4 += bflo((q)[2]); a5 += bfhi((q)[2]); a6 += bflo((q)[3]); a7 += bfhi((q)[3]);

__global__ __launch_bounds__(256) void aggregate_kernel(const char* __restrict__ xsb,
                                                        const int* __restrict__ rowptr,
                                                        const u16* __restrict__ col,
                                                        const float* __restrict__ dis,
                                                        char* __restrict__ ob, int N){
  const int f   = blockIdx.x & 7;          // feature slice -> XCD (b%8 round-robin)
  const int grp = blockIdx.x >> 3;
  const int v   = grp * 4 + (threadIdx.x >> 6);
  if (v >= N) return;
  const int lane = threadIdx.x & 63;
  const int eg   = lane >> 3;              // edge slot within 8-edge chunk
  const u32 soff = (u32)((f << 7) + ((lane & 7) << 4));  // byte offset in 1KB row

  auto ld = [&](u32 node) -> u32x4 {
    return *(const u32x4*)(xsb + (((size_t)node << 10) + soff));
  };

  const int e0 = rowptr[v];
  const int m  = (rowptr[v + 1] - e0) >> 3;   // >= 1 (self edge guarantees)
  const u16* cp = col + e0;

  float a0=0.f,a1=0.f,a2=0.f,a3=0.f,a4=0.f,a5=0.f,a6=0.f,a7=0.f;

  u32x4 qa = ld((u32)cp[eg]);
  u32x4 qb = qa;                        // init for m==1 path safety (not consumed)
  const bool has2 = (m > 1);
  if (has2) qb = ld((u32)cp[8 + eg]);

  for (int i = 0; i + 2 < m; ++i){      // all indices stay in-list: no wasted gathers
    u32x4 qc = ld((u32)cp[8 * (i + 2) + eg]);
    ACCQ(qa);
    qa = qb; qb = qc;
  }
  if (has2){ ACCQ(qa); ACCQ(qb); }
  else     { ACCQ(qa); }

  // butterfly reduce across the 8 edge-groups (lanes ^8, ^16, ^32)
  #define RED8(mask) \
    a0 += __shfl_xor(a0, mask); a1 += __shfl_xor(a1, mask); \
    a2 += __shfl_xor(a2, mask); a3 += __shfl_xor(a3, mask); \
    a4 += __shfl_xor(a4, mask); a5 += __shfl_xor(a5, mask); \
    a6 += __shfl_xor(a6, mask); a7 += __shfl_xor(a7, mask);
  RED8(8) RED8(16) RED8(32)
  #undef RED8

  if (eg == 0){
    const float dv = dis[v];
    u32x4 r;
    r[0] = ((u32)f2bf(dv * a1) << 16) | f2bf(dv * a0);
    r[1] = ((u32)f2bf(dv * a3) << 16) | f2bf(dv * a2);
    r[2] = ((u32)f2bf(dv * a5) << 16) | f2bf(dv * a4);
    r[3] = ((u32)f2bf(dv * a7) << 16) | f2bf(dv * a6);
    *(u32x4*)(ob + (((size_t)v) << 10) + soff) = r;
  }
}

// ---------------- GEMM: BM=128 x BN=512(full) x BK=32, 512 thr (8 waves 2Mx4N) ----------------
// (unchanged from r12 for clean A/B on the aggregate)

__global__ __launch_bounds__(512) void gemm_kernel(const u16* __restrict__ A,
                                                   const u16* __restrict__ Bt,
                                                   const float* __restrict__ bias,
                                                   const float* __restrict__ dis,
                                                   u16* __restrict__ Cb,
                                                   float* __restrict__ Cf,
                                                   int n_real, int last){
  extern __shared__ u16 smem[];
  u16* const sAb = smem;            // [2][128*32] u16
  u16* const sBb = smem + 8192;     // [2][512*32] u16

  const int cpx = gridDim.x >> 3;
  const int wg  = (blockIdx.x & 7) * cpx + (blockIdx.x >> 3);
  const int bm0 = wg << 7;

  const int tid  = threadIdx.x;
  const int lane = tid & 63;
  const int wv   = tid >> 6;        // 0..7
  const int wm   = wv >> 2;         // 0..1 -> 64-row half
  const int wn   = wv & 3;          // 0..3 -> 128-col quarter
  const int lr   = lane & 15, lg = lane >> 4;

  f32x4 acc[4][8] = {};

  auto stage = [&](int bsel, int t){
    const int k0 = t << 5;
    u16* dA = sAb + (bsel << 12);
    u16* dB = sBb + (bsel << 14);
    {
      const int row = tid >> 2;
      const int gq  = ((tid & 3) ^ ((row >> 1) & 3)) << 3;   // pre-swizzled global chunk
      gload_lds16(A + (((size_t)(bm0 + row)) << 9) + k0 + gq,
                  (void*)&dA[(row << 5) + ((tid & 3) << 3)]); // linear dest
    }
    #pragma unroll
    for (int p = 0; p < 4; ++p){
      const int row = (tid >> 2) + (p << 7);
      const int gq  = ((tid & 3) ^ ((row >> 1) & 3)) << 3;
      gload_lds16(Bt + (((size_t)row) << 9) + k0 + gq,
                  (void*)&dB[(row << 5) + ((tid & 3) << 3)]);
    }
  };

  stage(0, 0);   // 5 loads/thread per stage
  stage(1, 1);   // 10 outstanding after prologue

  #pragma unroll
  for (int t = 0; t < 16; ++t){
    const int cur = t & 1;
    if (t < 15) asm volatile("s_waitcnt vmcnt(5)" ::: "memory");
    else        asm volatile("s_waitcnt vmcnt(0)" ::: "memory");
    __builtin_amdgcn_s_barrier();
    __builtin_amdgcn_sched_barrier(0);

    const bf16x8* A8 = (const bf16x8*)(sAb + (cur << 12));
    const bf16x8* B8 = (const bf16x8*)(sBb + (cur << 14));
    __builtin_amdgcn_s_setprio(1);
    bf16x8 af[4], bg[8];
    #pragma unroll
    for (int mi = 0; mi < 4; ++mi){
      const int row = (wm << 6) + (mi << 4) + lr;
      af[mi] = A8[(row << 2) + (lg ^ ((row >> 1) & 3))];     // read-side swizzle
    }
    #pragma unroll
    for (int ni = 0; ni < 8; ++ni){
      const int row = (wn << 7) + (ni << 4) + lr;
      bg[ni] = B8[(row << 2) + (lg ^ ((row >> 1) & 3))];
    }
    #pragma unroll
    for (int mi = 0; mi < 4; ++mi)
      #pragma unroll
      for (int ni = 0; ni < 8; ++ni)
        acc[mi][ni] = __builtin_amdgcn_mfma_f32_16x16x32_bf16(af[mi], bg[ni], acc[mi][ni], 0, 0, 0);
    __builtin_amdgcn_s_setprio(0);
    __builtin_amdgcn_sched_barrier(0);
    __builtin_amdgcn_s_barrier();      // all waves done reading buf[cur]
    if (t < 14) stage(cur, t + 2);     // refill freed buffer
  }

  float bb[8];
  #pragma unroll
  for (int ni = 0; ni < 8; ++ni) bb[ni] = bias[(wn << 7) + (ni << 4) + lr];

  // C/D layout: col=lane&15, row=(lane>>4)*4+reg  [m89-verified]
  #pragma unroll
  for (int mi = 0; mi < 4; ++mi){
    const int row0 = bm0 + (wm << 6) + (mi << 4) + (lg << 2);
    const f32x4 dv4 = *(const f32x4*)(dis + row0);   // dis padded; rows>=n_real unused
    #pragma unroll
    for (int ni = 0; ni < 8; ++ni){
      const int c0 = (wn << 7) + (ni << 4) + lr;
      #pragma unroll
      for (int r = 0; r < 4; ++r){
        const int row = row0 + r;
        const float val = fmaxf(acc[mi][ni][r] + bb[ni], 0.f);
        if (!last){
          Cb[(((size_t)row) << 9) + c0] = (row < n_real) ? f2bf(dv4[r] * val) : (u16)0;
        } else if (row < n_real){
          Cf[(((size_t)row) << 9) + c0] = val;
        }
      }
    }
  }
}

// ---------------- launch ----------------

extern "C" void kernel_launch(void* const* d_in, const int* in_sizes, int n_in,
                              void* d_out, int out_size, void* d_ws, size_t ws_size,
                              hipStream_t stream) {
  const float* x    = (const float*)d_in[0];
  const int*   ei   = (const int*)d_in[1];   // [2][E] int32: src = ei, dst = ei + E
  const float* W    = (const float*)d_in[2]; // [L][512][512]
  const float* bias = (const float*)d_in[3]; // [L][512]
  float* out = (float*)d_out;

  const int N = in_sizes[0] >> 9;       // 50000
  const int E = in_sizes[1] >> 1;       // 800000
  const int L = in_sizes[3] >> 9;       // 3
  const int MPAD = (N + 255) & ~255;    // 50176 (> N so row N is a zero pad row)
  const int NB = (N + 1023) / 1024;     // scan blocks (49)

  char* p = (char*)d_ws;
  auto alloc = [&](size_t bytes){ char* q = p; p += (bytes + 255) & ~(size_t)255; return q; };
  u16*   xb       = (u16*)alloc((size_t)MPAD * 512 * 2);
  u16*   aggb     = (u16*)alloc((size_t)MPAD * 512 * 2);
  u16*   wt       = (u16*)alloc((size_t)L * 512 * 512 * 2);
  float* dis      = (float*)alloc((size_t)(MPAD + 4) * 4);  // padded for epilogue f32x4 reads
  int*   rowptr_d = (int*)alloc((size_t)(N + 1) * 4);
  int*   cursor_d = (int*)alloc((size_t)N * 4);
  int*   cnt_d    = (int*)alloc((size_t)N * 4);
  u16*   col      = (u16*)alloc(((size_t)E + 9 * (size_t)N + 64) * 2);  // +self edges +padding
  int*   bsums_d  = (int*)alloc(256 * 4);

  hipFuncSetAttribute((const void*)gemm_kernel,
                      hipFuncAttributeMaxDynamicSharedMemorySize, 81920);

  hipMemsetAsync(cnt_d, 0, (size_t)N * 4, stream);
  hipMemsetAsync(aggb + (size_t)N * 512, 0, (size_t)(MPAD - N) * 512 * 2, stream);

  // P1: count_deg (vec4) || convert_w (transpose tiles)
  const int CB = (E / 4 + 255) / 256;     // 782
  prep1_kernel<<<CB + L * 64, 256, 0, stream>>>(ei + E, E, CB, cnt_d, W, wt);

  scan1_kernel<<<NB, 1024, 0, stream>>>(cnt_d, N, rowptr_d, bsums_d);
  scan2_kernel<<<1, 256, 0, stream>>>(bsums_d, NB);
  finalize_kernel<<<(N + 255) / 256, 256, 0, stream>>>(rowptr_d, cursor_d, bsums_d, NB, cnt_d, dis, N);

  // P3: convert_x || fill_csr || pad_fill(+self)
  const int ntot = MPAD * 512;
  const int XB = (ntot / 8 + 255) / 256;  // 12544
  const int FB = (E + 255) / 256;         // 3125
  const int PB = (N + 255) / 256;         // 196
  prep3_kernel<<<XB + FB + PB, 256, 0, stream>>>(x, dis, (u32*)xb, N * 512, ntot, XB,
                                                 ei, ei + E, E, FB,
                                                 cursor_d, rowptr_d, cnt_d, N, col);

  const int ggrid = MPAD / 128;         // 392 = 8*49, divisible by 8
  const int agrid = ((N + 3) / 4) * 8;  // node-groups x 8 slices
  for (int l = 0; l < L; ++l){
    aggregate_kernel<<<agrid, 256, 0, stream>>>((const char*)xb, rowptr_d, col, dis,
                                                (char*)aggb, N);
    gemm_kernel<<<ggrid, 512, 81920, stream>>>(aggb, wt + (size_t)l * 512 * 512,
                                               bias + (size_t)l * 512, dis,
                                               xb, out, N, (l == L - 1) ? 1 : 0);
  }
}

// Round 15
// 574.905 us; speedup vs baseline: 1.3249x; 1.3249x over previous
//
#include <hip/hip_runtime.h>
#include <hip/hip_bf16.h>

using u16 = unsigned short;
using u32 = unsigned int;

typedef __bf16 bf16x8 __attribute__((ext_vector_type(8)));
typedef float  f32x4  __attribute__((ext_vector_type(4)));
typedef u32    u32x4  __attribute__((ext_vector_type(4)));
typedef u16    u16x8  __attribute__((ext_vector_type(8)));
typedef int    i32x4  __attribute__((ext_vector_type(4)));

__device__ __forceinline__ float bflo(u32 u){ union { u32 u; float f; } c; c.u = u << 16;          return c.f; }
__device__ __forceinline__ float bfhi(u32 u){ union { u32 u; float f; } c; c.u = u & 0xffff0000u;  return c.f; }
__device__ __forceinline__ u16  f2bf(float f){
  union { float f; u32 u; } c; c.f = f;
  u32 u = c.u;
  return (u16)((u + 0x7fffu + ((u >> 16) & 1u)) >> 16); // RNE
}

__device__ __forceinline__ void gload_lds16(const void* g, void* l){
  __builtin_amdgcn_global_load_lds(
      (const __attribute__((address_space(1))) void*)g,
      (__attribute__((address_space(3))) void*)l, 16, 0, 0);
}

// ---------------- fused prep P1: count_deg (vec4) || convert_w (tiled transpose) ----------------

__global__ __launch_bounds__(256) void prep1_kernel(const int* __restrict__ dst, int E, int CB,
                                                    int* __restrict__ cnt,
                                                    const float* __restrict__ W,
                                                    u16* __restrict__ Wt){
  if ((int)blockIdx.x < CB){
    int i4 = (blockIdx.x * 256 + threadIdx.x) * 4;
    if (i4 + 3 < E){
      i32x4 d = *(const i32x4*)(dst + i4);
      atomicAdd(&cnt[d[0]], 1); atomicAdd(&cnt[d[1]], 1);
      atomicAdd(&cnt[d[2]], 1); atomicAdd(&cnt[d[3]], 1);
    } else {
      for (int i = i4; i < E; ++i) atomicAdd(&cnt[dst[i]], 1);
    }
    return;
  }
  // ---- W transpose tile: Wt[l][n][k] = bf16(W[l][k][n]) ----
  __shared__ u16 tile[64][72];
  const int tix = blockIdx.x - CB;        // 0 .. L*64-1
  const int l   = tix >> 6;
  const int kt  = ((tix >> 3) & 7) << 6;  // k tile base
  const int nt  = (tix & 7) << 6;         // n tile base
  const int tid = threadIdx.x;
  const int ty  = tid >> 4;               // 0..15
  const int tx  = tid & 15;               // 0..15 (4 floats each)
  const float* Wl = W + ((size_t)l << 18);
  #pragma unroll
  for (int q = 0; q < 4; ++q){
    const int row = (q << 4) + ty;        // k within tile
    f32x4 v = *(const f32x4*)(Wl + (((size_t)(kt + row)) << 9) + nt + (tx << 2));
    #pragma unroll
    for (int j = 0; j < 4; ++j) tile[(tx << 2) + j][row] = f2bf(v[j]);
  }
  __syncthreads();
  u16* Wtl = Wt + ((size_t)l << 18);
  #pragma unroll
  for (int rep = 0; rep < 2; ++rep){
    const int idx  = (rep << 8) + tid;    // 0..511
    const int nrow = idx >> 3;            // 0..63
    const int ch   = idx & 7;             // 8-u16 chunk
    u16x8 o;
    #pragma unroll
    for (int j = 0; j < 8; ++j) o[j] = tile[nrow][(ch << 3) + j];
    *(u16x8*)(Wtl + (((size_t)(nt + nrow)) << 9) + kt + (ch << 3)) = o;
  }
}

// ---------------- scan chain ----------------

__global__ void scan1_kernel(const int* __restrict__ cnt, int n,
                             int* __restrict__ excl, int* __restrict__ bsums){
  __shared__ int sd[1024];
  const int tid = threadIdx.x;
  const int i = blockIdx.x * 1024 + tid;
  int v = 0;
  if (i < n) v = (cnt[i] + 1 + 7) & ~7;   // +1 self edge, pad to multiple of 8 (>= 8)
  sd[tid] = v;
  __syncthreads();
  for (int s = 1; s < 1024; s <<= 1){
    int t = (tid >= s) ? sd[tid - s] : 0;
    __syncthreads();
    sd[tid] += t;
    __syncthreads();
  }
  if (i < n) excl[i] = sd[tid] - v;
  if (tid == 1023) bsums[blockIdx.x] = sd[tid];
}

__global__ void scan2_kernel(int* __restrict__ bsums, int nb){
  __shared__ int sd[256];
  const int tid = threadIdx.x;
  int v = (tid < nb) ? bsums[tid] : 0;
  sd[tid] = v;
  __syncthreads();
  for (int s = 1; s < 256; s <<= 1){
    int t = (tid >= s) ? sd[tid - s] : 0;
    __syncthreads();
    sd[tid] += t;
    __syncthreads();
  }
  if (tid < nb) bsums[tid] = sd[tid] - v;
  if (tid == nb - 1) bsums[nb] = sd[tid];
}

__global__ void finalize_kernel(int* __restrict__ rowptr, int* __restrict__ cursor,
                                const int* __restrict__ bsums, int nb,
                                const int* __restrict__ cnt,
                                float* __restrict__ dis, int n){
  int i = blockIdx.x * blockDim.x + threadIdx.x;
  if (i < n){
    int r = rowptr[i] + bsums[i >> 10];
    rowptr[i] = r;
    cursor[i] = r;
    dis[i] = rsqrtf((float)(cnt[i] + 1)); // +1 self loop
  }
  if (i == 0){
    rowptr[n] = bsums[nb];
    dis[n] = 0.f;                          // sentinel node
  }
}

// ---------------- m-sort: counting sort of nodes by padded chunk count (perf-only perm) ------
// m(v) = (cnt[v]+8)>>3 clamped to 31. Per-block LDS hists -> single-block scan -> LDS scatter.

__global__ __launch_bounds__(256) void mhist_kernel(const int* __restrict__ cnt, int N, int NBH,
                                                    int* __restrict__ bh){
  __shared__ int h[32];
  if (threadIdx.x < 32) h[threadIdx.x] = 0;
  __syncthreads();
  int v = blockIdx.x * 256 + threadIdx.x;
  if (v < N) atomicAdd(&h[min((cnt[v] + 8) >> 3, 31)], 1);
  __syncthreads();
  if (threadIdx.x < 32) bh[threadIdx.x * NBH + blockIdx.x] = h[threadIdx.x];  // bin-major
}

__global__ void mscan_kernel(int* __restrict__ bh, int total){
  __shared__ int sd[1024];
  int off = 0;
  for (int base = 0; base < total; base += 1024){
    int i = base + threadIdx.x;
    int val = (i < total) ? bh[i] : 0;
    sd[threadIdx.x] = val;
    __syncthreads();
    for (int s = 1; s < 1024; s <<= 1){
      int t = (threadIdx.x >= s) ? sd[threadIdx.x - s] : 0;
      __syncthreads();
      sd[threadIdx.x] += t;
      __syncthreads();
    }
    if (i < total) bh[i] = off + sd[threadIdx.x] - val;
    off += sd[1023];
    __syncthreads();
  }
}

__global__ __launch_bounds__(256) void mscatter_kernel(const int* __restrict__ cnt, int N, int NBH,
                                                       const int* __restrict__ bh,
                                                       int* __restrict__ perm){
  __shared__ int cur[32];
  if (threadIdx.x < 32) cur[threadIdx.x] = bh[threadIdx.x * NBH + blockIdx.x];
  __syncthreads();
  int v = blockIdx.x * 256 + threadIdx.x;
  if (v < N){
    int p = atomicAdd(&cur[min((cnt[v] + 8) >> 3, 31)], 1);
    perm[p] = v;
  }
}

// ---------------- fused prep P3: convert_x || fill_csr || pad_fill(+self edge) ----------------

__global__ __launch_bounds__(256) void prep3_kernel(const float* __restrict__ x,
                                                    const float* __restrict__ dis,
                                                    u32* __restrict__ xb,
                                                    int n_real, int n_tot, int XB,
                                                    const int* __restrict__ src,
                                                    const int* __restrict__ dst,
                                                    int E, int FB,
                                                    int* __restrict__ cursor,
                                                    const int* __restrict__ rowptr,
                                                    const int* __restrict__ cnt,
                                                    int N,
                                                    u16* __restrict__ col){
  const int b = blockIdx.x;
  if (b < XB){
    int i8 = (b * 256 + threadIdx.x) * 8;
    if (i8 >= n_tot) return;
    u32 q0, q1, q2, q3;
    if (i8 < n_real){
      const float dv = dis[i8 >> 9];
      const f32x4* xp = (const f32x4*)(x + i8);
      f32x4 a = xp[0], v = xp[1];
      q0 = ((u32)f2bf(dv * a[1]) << 16) | f2bf(dv * a[0]);
      q1 = ((u32)f2bf(dv * a[3]) << 16) | f2bf(dv * a[2]);
      q2 = ((u32)f2bf(dv * v[1]) << 16) | f2bf(dv * v[0]);
      q3 = ((u32)f2bf(dv * v[3]) << 16) | f2bf(dv * v[2]);
    } else {
      q0 = q1 = q2 = q3 = 0u;  // pad rows (incl. sentinel N) stay zero
    }
    u32x4 q = {q0, q1, q2, q3};
    *(u32x4*)(xb + (i8 >> 1)) = q;
  } else if (b < XB + FB){
    int i = (b - XB) * 256 + threadIdx.x;
    if (i < E){
      int d = dst[i];
      int p = atomicAdd(&cursor[d], 1);
      col[p] = (u16)src[i];
    }
  } else {
    int v = (b - XB - FB) * 256 + threadIdx.x;
    if (v < N){
      int p = rowptr[v] + cnt[v];
      col[p++] = (u16)v;                   // self edge: dis[v]*xs[v] == dv^2*x[v]
      const int p1 = rowptr[v + 1];
      for (; p < p1; ++p) col[p] = (u16)N; // sentinel padding (xs[N]=0)
    }
    if (v == 0){
      int t = rowptr[N];
      for (int j = 0; j < 32; ++j) col[t + j] = (u16)N;
    }
  }
}

// ---------------- aggregation: XCD-sliced, 8 nodes x 8 lanes per wave, no cross-lane reduce ----
// block b: slice f = b&7 (-> XCD b&7); wave handles 8 m-sorted nodes (perm); each 8-lane
// group owns one node's 128B slice; each lane accumulates its 16B across edges in-register.
// Iso-instruction with r12 (1 gather instr = 8 nodes x 1 edge x 128B = 16 lines), but
// per-XCD footprint 51MB -> 6.4MB. Equal-m waves (sorted) -> uniform loops; tail via
// sentinel-splat cols (row N zeros, dis[N]=0).

#define GATHER8(p, c) \
  p##0 = ld((u32)(c)[0]); p##1 = ld((u32)(c)[1]); p##2 = ld((u32)(c)[2]); p##3 = ld((u32)(c)[3]); \
  p##4 = ld((u32)(c)[4]); p##5 = ld((u32)(c)[5]); p##6 = ld((u32)(c)[6]); p##7 = ld((u32)(c)[7]);

#define ACCQ(q) \
  a0 += bflo((q)[0]); a1 += bfhi((q)[0]); a2 += bflo((q)[1]); a3 += bfhi((q)[1]); \
  a4 += bflo((q)[2]); a5 += bfhi((q)[2]); a6 += bflo((q)[3]); a7 += bfhi((q)[3]);

#define CONS8(p) \
  ACCQ(p##0) ACCQ(p##1) ACCQ(p##2) ACCQ(p##3) ACCQ(p##4) ACCQ(p##5) ACCQ(p##6) ACCQ(p##7)

__global__ __launch_bounds__(256) void aggregate_kernel(const char* __restrict__ xsb,
                                                        const int* __restrict__ rowptr,
                                                        const u16* __restrict__ col,
                                                        const float* __restrict__ dis,
                                                        const int* __restrict__ perm,
                                                        char* __restrict__ ob, int N){
  const int f    = blockIdx.x & 7;                 // feature slice -> XCD
  const int widx = (blockIdx.x >> 3) * 4 + (threadIdx.x >> 6);
  const int lane = threadIdx.x & 63;
  const int g    = lane >> 3;                      // node group within wave
  const int pc   = lane & 7;                       // 16B piece within 128B slice
  const int idx  = widx * 8 + g;
  const u32 soff = (u32)((f << 7) + (pc << 4));

  int v, e0, mg;
  if (idx < N){ v = perm[idx]; e0 = rowptr[v]; mg = (rowptr[v + 1] - e0) >> 3; }
  else        { v = N;         e0 = rowptr[N]; mg = 1; }   // sentinel tail slots
  const u16* cp = col + e0;

  // wave-uniform loop bound (sorted perm -> usually mg == M for all groups)
  int M = mg;
  M = max(M, __shfl_xor(M, 8));
  M = max(M, __shfl_xor(M, 16));
  M = max(M, __shfl_xor(M, 32));

  auto ld = [&](u32 node) -> u32x4 {
    return *(const u32x4*)(xsb + (((size_t)node << 10) + soff));
  };
  auto ldc = [&](int k) -> u16x8 {
    u16x8 r;
    if (k < mg){
      r = *(const u16x8*)(cp + (k << 3));
    } else {
      #pragma unroll
      for (int j = 0; j < 8; ++j) r[j] = (u16)N;   // sentinel: zero row, adds 0
    }
    return r;
  };

  float a0=0.f,a1=0.f,a2=0.f,a3=0.f,a4=0.f,a5=0.f,a6=0.f,a7=0.f;

  u32x4 qa0, qa1, qa2, qa3, qa4, qa5, qa6, qa7;
  u32x4 qb0, qb1, qb2, qb3, qb4, qb5, qb6, qb7;

  u16x8 c0 = ldc(0);
  u16x8 c1 = ldc(1);
  GATHER8(qa, c0);

  int i = 1;
  for (; i + 1 < M; i += 2){
    c0 = ldc(i + 1);
    GATHER8(qb, c1);
    CONS8(qa);
    c1 = ldc(i + 2);
    GATHER8(qa, c0);
    CONS8(qb);
  }
  if (i < M){
    GATHER8(qb, c1);
    CONS8(qa);
    CONS8(qb);
  } else {
    CONS8(qa);
  }

  const float dv = dis[v];                          // dis[N] = 0 -> pad rows stay zero
  u32x4 r;
  r[0] = ((u32)f2bf(dv * a1) << 16) | f2bf(dv * a0);
  r[1] = ((u32)f2bf(dv * a3) << 16) | f2bf(dv * a2);
  r[2] = ((u32)f2bf(dv * a5) << 16) | f2bf(dv * a4);
  r[3] = ((u32)f2bf(dv * a7) << 16) | f2bf(dv * a6);
  *(u32x4*)(ob + (((size_t)v) << 10) + soff) = r;
}

// ---------------- GEMM: BM=128 x BN=512(full) x BK=32, 512 thr (unchanged from r12) ----------

__global__ __launch_bounds__(512) void gemm_kernel(const u16* __restrict__ A,
                                                   const u16* __restrict__ Bt,
                                                   const float* __restrict__ bias,
                                                   const float* __restrict__ dis,
                                                   u16* __restrict__ Cb,
                                                   float* __restrict__ Cf,
                                                   int n_real, int last){
  extern __shared__ u16 smem[];
  u16* const sAb = smem;            // [2][128*32] u16
  u16* const sBb = smem + 8192;     // [2][512*32] u16

  const int cpx = gridDim.x >> 3;
  const int wg  = (blockIdx.x & 7) * cpx + (blockIdx.x >> 3);
  const int bm0 = wg << 7;

  const int tid  = threadIdx.x;
  const int lane = tid & 63;
  const int wv   = tid >> 6;        // 0..7
  const int wm   = wv >> 2;         // 0..1 -> 64-row half
  const int wn   = wv & 3;          // 0..3 -> 128-col quarter
  const int lr   = lane & 15, lg = lane >> 4;

  f32x4 acc[4][8] = {};

  auto stage = [&](int bsel, int t){
    const int k0 = t << 5;
    u16* dA = sAb + (bsel << 12);
    u16* dB = sBb + (bsel << 14);
    {
      const int row = tid >> 2;
      const int gq  = ((tid & 3) ^ ((row >> 1) & 3)) << 3;   // pre-swizzled global chunk
      gload_lds16(A + (((size_t)(bm0 + row)) << 9) + k0 + gq,
                  (void*)&dA[(row << 5) + ((tid & 3) << 3)]); // linear dest
    }
    #pragma unroll
    for (int p = 0; p < 4; ++p){
      const int row = (tid >> 2) + (p << 7);
      const int gq  = ((tid & 3) ^ ((row >> 1) & 3)) << 3;
      gload_lds16(Bt + (((size_t)row) << 9) + k0 + gq,
                  (void*)&dB[(row << 5) + ((tid & 3) << 3)]);
    }
  };

  stage(0, 0);   // 5 loads/thread per stage
  stage(1, 1);   // 10 outstanding after prologue

  #pragma unroll
  for (int t = 0; t < 16; ++t){
    const int cur = t & 1;
    if (t < 15) asm volatile("s_waitcnt vmcnt(5)" ::: "memory");
    else        asm volatile("s_waitcnt vmcnt(0)" ::: "memory");
    __builtin_amdgcn_s_barrier();
    __builtin_amdgcn_sched_barrier(0);

    const bf16x8* A8 = (const bf16x8*)(sAb + (cur << 12));
    const bf16x8* B8 = (const bf16x8*)(sBb + (cur << 14));
    __builtin_amdgcn_s_setprio(1);
    bf16x8 af[4], bg[8];
    #pragma unroll
    for (int mi = 0; mi < 4; ++mi){
      const int row = (wm << 6) + (mi << 4) + lr;
      af[mi] = A8[(row << 2) + (lg ^ ((row >> 1) & 3))];     // read-side swizzle
    }
    #pragma unroll
    for (int ni = 0; ni < 8; ++ni){
      const int row = (wn << 7) + (ni << 4) + lr;
      bg[ni] = B8[(row << 2) + (lg ^ ((row >> 1) & 3))];
    }
    #pragma unroll
    for (int mi = 0; mi < 4; ++mi)
      #pragma unroll
      for (int ni = 0; ni < 8; ++ni)
        acc[mi][ni] = __builtin_amdgcn_mfma_f32_16x16x32_bf16(af[mi], bg[ni], acc[mi][ni], 0, 0, 0);
    __builtin_amdgcn_s_setprio(0);
    __builtin_amdgcn_sched_barrier(0);
    __builtin_amdgcn_s_barrier();      // all waves done reading buf[cur]
    if (t < 14) stage(cur, t + 2);     // refill freed buffer
  }

  float bb[8];
  #pragma unroll
  for (int ni = 0; ni < 8; ++ni) bb[ni] = bias[(wn << 7) + (ni << 4) + lr];

  // C/D layout: col=lane&15, row=(lane>>4)*4+reg  [m89-verified]
  #pragma unroll
  for (int mi = 0; mi < 4; ++mi){
    const int row0 = bm0 + (wm << 6) + (mi << 4) + (lg << 2);
    const f32x4 dv4 = *(const f32x4*)(dis + row0);   // dis padded; rows>=n_real unused
    #pragma unroll
    for (int ni = 0; ni < 8; ++ni){
      const int c0 = (wn << 7) + (ni << 4) + lr;
      #pragma unroll
      for (int r = 0; r < 4; ++r){
        const int row = row0 + r;
        const float val = fmaxf(acc[mi][ni][r] + bb[ni], 0.f);
        if (!last){
          Cb[(((size_t)row) << 9) + c0] = (row < n_real) ? f2bf(dv4[r] * val) : (u16)0;
        } else if (row < n_real){
          Cf[(((size_t)row) << 9) + c0] = val;
        }
      }
    }
  }
}

// ---------------- launch ----------------

extern "C" void kernel_launch(void* const* d_in, const int* in_sizes, int n_in,
                              void* d_out, int out_size, void* d_ws, size_t ws_size,
                              hipStream_t stream) {
  const float* x    = (const float*)d_in[0];
  const int*   ei   = (const int*)d_in[1];   // [2][E] int32: src = ei, dst = ei + E
  const float* W    = (const float*)d_in[2]; // [L][512][512]
  const float* bias = (const float*)d_in[3]; // [L][512]
  float* out = (float*)d_out;

  const int N = in_sizes[0] >> 9;       // 50000
  const int E = in_sizes[1] >> 1;       // 800000
  const int L = in_sizes[3] >> 9;       // 3
  const int MPAD = (N + 255) & ~255;    // 50176 (> N so row N is a zero pad row)
  const int NB = (N + 1023) / 1024;     // scan blocks (49)
  const int NBH = (N + 255) / 256;      // m-sort blocks (196)

  char* p = (char*)d_ws;
  auto alloc = [&](size_t bytes){ char* q = p; p += (bytes + 255) & ~(size_t)255; return q; };
  u16*   xb       = (u16*)alloc((size_t)MPAD * 512 * 2);
  u16*   aggb     = (u16*)alloc((size_t)MPAD * 512 * 2);
  u16*   wt       = (u16*)alloc((size_t)L * 512 * 512 * 2);
  float* dis      = (float*)alloc((size_t)(MPAD + 4) * 4);  // padded for epilogue f32x4 reads
  int*   rowptr_d = (int*)alloc((size_t)(N + 1) * 4);
  int*   cursor_d = (int*)alloc((size_t)N * 4);
  int*   cnt_d    = (int*)alloc((size_t)N * 4);
  int*   perm     = (int*)alloc((size_t)N * 4);
  int*   bh       = (int*)alloc((size_t)32 * NBH * 4);
  u16*   col      = (u16*)alloc(((size_t)E + 9 * (size_t)N + 64) * 2);  // +self edges +padding
  int*   bsums_d  = (int*)alloc(256 * 4);

  hipFuncSetAttribute((const void*)gemm_kernel,
                      hipFuncAttributeMaxDynamicSharedMemorySize, 81920);

  hipMemsetAsync(cnt_d, 0, (size_t)N * 4, stream);
  hipMemsetAsync(aggb + (size_t)N * 512, 0, (size_t)(MPAD - N) * 512 * 2, stream);

  // P1: count_deg (vec4) || convert_w (transpose tiles)
  const int CB = (E / 4 + 255) / 256;     // 782
  prep1_kernel<<<CB + L * 64, 256, 0, stream>>>(ei + E, E, CB, cnt_d, W, wt);

  scan1_kernel<<<NB, 1024, 0, stream>>>(cnt_d, N, rowptr_d, bsums_d);
  scan2_kernel<<<1, 256, 0, stream>>>(bsums_d, NB);
  finalize_kernel<<<(N + 255) / 256, 256, 0, stream>>>(rowptr_d, cursor_d, bsums_d, NB, cnt_d, dis, N);

  // m-sort (perf-only node permutation for divergence-free 8-node waves)
  mhist_kernel<<<NBH, 256, 0, stream>>>(cnt_d, N, NBH, bh);
  mscan_kernel<<<1, 1024, 0, stream>>>(bh, 32 * NBH);
  mscatter_kernel<<<NBH, 256, 0, stream>>>(cnt_d, N, NBH, bh, perm);

  // P3: convert_x || fill_csr || pad_fill(+self)
  const int ntot = MPAD * 512;
  const int XB = (ntot / 8 + 255) / 256;  // 12544
  const int FB = (E + 255) / 256;         // 3125
  const int PB = (N + 255) / 256;         // 196
  prep3_kernel<<<XB + FB + PB, 256, 0, stream>>>(x, dis, (u32*)xb, N * 512, ntot, XB,
                                                 ei, ei + E, E, FB,
                                                 cursor_d, rowptr_d, cnt_d, N, col);

  const int ggrid = MPAD / 128;           // 392 = 8*49, divisible by 8
  const int agrid = ((N + 31) / 32) * 8;  // 32 nodes/block x 8 slices
  for (int l = 0; l < L; ++l){
    aggregate_kernel<<<agrid, 256, 0, stream>>>((const char*)xb, rowptr_d, col, dis,
                                                perm, (char*)aggb, N);
    gemm_kernel<<<ggrid, 512, 81920, stream>>>(aggb, wt + (size_t)l * 512 * 512,
                                               bias + (size_t)l * 512, dis,
                                               xb, out, N, (l == L - 1) ? 1 : 0);
  }
}

// Round 16
// 538.041 us; speedup vs baseline: 1.4157x; 1.0685x over previous
//
#include <hip/hip_runtime.h>
#include <hip/hip_bf16.h>

using u16 = unsigned short;
using u32 = unsigned int;

typedef __bf16 bf16x8 __attribute__((ext_vector_type(8)));
typedef float  f32x4  __attribute__((ext_vector_type(4)));
typedef u32    u32x4  __attribute__((ext_vector_type(4)));
typedef u16    u16x8  __attribute__((ext_vector_type(8)));
typedef int    i32x4  __attribute__((ext_vector_type(4)));

__device__ __forceinline__ float bflo(u32 u){ union { u32 u; float f; } c; c.u = u << 16;          return c.f; }
__device__ __forceinline__ float bfhi(u32 u){ union { u32 u; float f; } c; c.u = u & 0xffff0000u;  return c.f; }
__device__ __forceinline__ u16  f2bf(float f){
  union { float f; u32 u; } c; c.f = f;
  u32 u = c.u;
  return (u16)((u + 0x7fffu + ((u >> 16) & 1u)) >> 16); // RNE
}

__device__ __forceinline__ void gload_lds16(const void* g, void* l){
  __builtin_amdgcn_global_load_lds(
      (const __attribute__((address_space(1))) void*)g,
      (__attribute__((address_space(3))) void*)l, 16, 0, 0);
}

// ---------------- fused prep P1: count_deg (vec4) || convert_w (tiled transpose) ----------------

__global__ __launch_bounds__(256) void prep1_kernel(const int* __restrict__ dst, int E, int CB,
                                                    int* __restrict__ cnt,
                                                    const float* __restrict__ W,
                                                    u16* __restrict__ Wt){
  if ((int)blockIdx.x < CB){
    int i4 = (blockIdx.x * 256 + threadIdx.x) * 4;
    if (i4 + 3 < E){
      i32x4 d = *(const i32x4*)(dst + i4);
      atomicAdd(&cnt[d[0]], 1); atomicAdd(&cnt[d[1]], 1);
      atomicAdd(&cnt[d[2]], 1); atomicAdd(&cnt[d[3]], 1);
    } else {
      for (int i = i4; i < E; ++i) atomicAdd(&cnt[dst[i]], 1);
    }
    return;
  }
  // ---- W transpose tile: Wt[l][n][k] = bf16(W[l][k][n]) ----
  __shared__ u16 tile[64][72];
  const int tix = blockIdx.x - CB;        // 0 .. L*64-1
  const int l   = tix >> 6;
  const int kt  = ((tix >> 3) & 7) << 6;  // k tile base
  const int nt  = (tix & 7) << 6;         // n tile base
  const int tid = threadIdx.x;
  const int ty  = tid >> 4;               // 0..15
  const int tx  = tid & 15;               // 0..15 (4 floats each)
  const float* Wl = W + ((size_t)l << 18);
  #pragma unroll
  for (int q = 0; q < 4; ++q){
    const int row = (q << 4) + ty;        // k within tile
    f32x4 v = *(const f32x4*)(Wl + (((size_t)(kt + row)) << 9) + nt + (tx << 2));
    #pragma unroll
    for (int j = 0; j < 4; ++j) tile[(tx << 2) + j][row] = f2bf(v[j]);
  }
  __syncthreads();
  u16* Wtl = Wt + ((size_t)l << 18);
  #pragma unroll
  for (int rep = 0; rep < 2; ++rep){
    const int idx  = (rep << 8) + tid;    // 0..511
    const int nrow = idx >> 3;            // 0..63
    const int ch   = idx & 7;             // 8-u16 chunk
    u16x8 o;
    #pragma unroll
    for (int j = 0; j < 8; ++j) o[j] = tile[nrow][(ch << 3) + j];
    *(u16x8*)(Wtl + (((size_t)(nt + nrow)) << 9) + kt + (ch << 3)) = o;
  }
}

// ---------------- scan chain ----------------

__global__ void scan1_kernel(const int* __restrict__ cnt, int n,
                             int* __restrict__ excl, int* __restrict__ bsums){
  __shared__ int sd[1024];
  const int tid = threadIdx.x;
  const int i = blockIdx.x * 1024 + tid;
  int v = 0;
  if (i < n) v = (cnt[i] + 1 + 7) & ~7;   // +1 self edge, pad to multiple of 8 (>= 8)
  sd[tid] = v;
  __syncthreads();
  for (int s = 1; s < 1024; s <<= 1){
    int t = (tid >= s) ? sd[tid - s] : 0;
    __syncthreads();
    sd[tid] += t;
    __syncthreads();
  }
  if (i < n) excl[i] = sd[tid] - v;
  if (tid == 1023) bsums[blockIdx.x] = sd[tid];
}

__global__ void scan2_kernel(int* __restrict__ bsums, int nb){
  __shared__ int sd[256];
  const int tid = threadIdx.x;
  int v = (tid < nb) ? bsums[tid] : 0;
  sd[tid] = v;
  __syncthreads();
  for (int s = 1; s < 256; s <<= 1){
    int t = (tid >= s) ? sd[tid - s] : 0;
    __syncthreads();
    sd[tid] += t;
    __syncthreads();
  }
  if (tid < nb) bsums[tid] = sd[tid] - v;
  if (tid == nb - 1) bsums[nb] = sd[tid];
}

__global__ void finalize_kernel(int* __restrict__ rowptr, int* __restrict__ cursor,
                                const int* __restrict__ bsums, int nb,
                                const int* __restrict__ cnt,
                                float* __restrict__ dis, int n){
  int i = blockIdx.x * blockDim.x + threadIdx.x;
  if (i < n){
    int r = rowptr[i] + bsums[i >> 10];
    rowptr[i] = r;
    cursor[i] = r;
    dis[i] = rsqrtf((float)(cnt[i] + 1)); // +1 self loop
  }
  if (i == 0){
    rowptr[n] = bsums[nb];
    dis[n] = 0.f;                          // sentinel node
  }
}

// ---------------- m-sort: counting sort of nodes by padded chunk count (perf-only perm) ------

__global__ __launch_bounds__(256) void mhist_kernel(const int* __restrict__ cnt, int N, int NBH,
                                                    int* __restrict__ bh){
  __shared__ int h[32];
  if (threadIdx.x < 32) h[threadIdx.x] = 0;
  __syncthreads();
  int v = blockIdx.x * 256 + threadIdx.x;
  if (v < N) atomicAdd(&h[min((cnt[v] + 8) >> 3, 31)], 1);
  __syncthreads();
  if (threadIdx.x < 32) bh[threadIdx.x * NBH + blockIdx.x] = h[threadIdx.x];  // bin-major
}

__global__ void mscan_kernel(int* __restrict__ bh, int total){
  __shared__ int sd[1024];
  int off = 0;
  for (int base = 0; base < total; base += 1024){
    int i = base + threadIdx.x;
    int val = (i < total) ? bh[i] : 0;
    sd[threadIdx.x] = val;
    __syncthreads();
    for (int s = 1; s < 1024; s <<= 1){
      int t = (threadIdx.x >= s) ? sd[threadIdx.x - s] : 0;
      __syncthreads();
      sd[threadIdx.x] += t;
      __syncthreads();
    }
    if (i < total) bh[i] = off + sd[threadIdx.x] - val;
    off += sd[1023];
    __syncthreads();
  }
}

__global__ __launch_bounds__(256) void mscatter_kernel(const int* __restrict__ cnt, int N, int NBH,
                                                       const int* __restrict__ bh,
                                                       int* __restrict__ perm){
  __shared__ int cur[32];
  if (threadIdx.x < 32) cur[threadIdx.x] = bh[threadIdx.x * NBH + blockIdx.x];
  __syncthreads();
  int v = blockIdx.x * 256 + threadIdx.x;
  if (v < N){
    int p = atomicAdd(&cur[min((cnt[v] + 8) >> 3, 31)], 1);
    perm[p] = v;
  }
}

// ---------------- fused prep P3: convert_x || fill_csr || pad_fill, INTERLEAVED ----------------
// Sections round-robin across the grid (4 CONV : 1 FILL/PAD per 5-block period) so the
// latency-bound atomic fill blocks are co-resident with the BW-bound convert blocks
// (r15: dispatch-order clustering serialized them -> 86.6us; overlap -> max not sum).
// FILL writes col[rowptr[v] .. rowptr[v]+cnt[v]) via cursor; PAD writes the disjoint
// tail [rowptr[v]+cnt[v], rowptr[v+1]) -> safe concurrently.

__global__ __launch_bounds__(256) void prep3_kernel(const float* __restrict__ x,
                                                    const float* __restrict__ dis,
                                                    u32* __restrict__ xb,
                                                    int n_real, int n_tot, int XB,
                                                    const int* __restrict__ src,
                                                    const int* __restrict__ dst,
                                                    int E, int FB, int PB,
                                                    int* __restrict__ cursor,
                                                    const int* __restrict__ rowptr,
                                                    const int* __restrict__ cnt,
                                                    int N,
                                                    u16* __restrict__ col){
  const int T5 = gridDim.x / 5;           // 'other' (FILL/PAD) slots
  const int q = blockIdx.x / 5, r = blockIdx.x % 5;
  int sec, idx;
  if (r == 4){
    if (q < FB){ sec = 1; idx = q; }
    else       { sec = 2; idx = q - FB; }
  } else {
    const int c = q * 4 + r;
    if (c < XB){ sec = 0; idx = c; }
    else       { sec = 2; idx = (c - XB) + (T5 - FB); }
  }

  if (sec == 0){
    int i8 = (idx * 256 + (int)threadIdx.x) * 8;
    if (i8 >= n_tot) return;
    u32 q0, q1, q2, q3;
    if (i8 < n_real){
      const float dv = dis[i8 >> 9];
      const f32x4* xp = (const f32x4*)(x + i8);
      f32x4 a = xp[0], v = xp[1];
      q0 = ((u32)f2bf(dv * a[1]) << 16) | f2bf(dv * a[0]);
      q1 = ((u32)f2bf(dv * a[3]) << 16) | f2bf(dv * a[2]);
      q2 = ((u32)f2bf(dv * v[1]) << 16) | f2bf(dv * v[0]);
      q3 = ((u32)f2bf(dv * v[3]) << 16) | f2bf(dv * v[2]);
    } else {
      q0 = q1 = q2 = q3 = 0u;  // pad rows (incl. sentinel N) stay zero
    }
    u32x4 qv = {q0, q1, q2, q3};
    *(u32x4*)(xb + (i8 >> 1)) = qv;
  } else if (sec == 1){
    int i = idx * 256 + threadIdx.x;
    if (i < E){
      int d = dst[i];
      int p = atomicAdd(&cursor[d], 1);
      col[p] = (u16)src[i];
    }
  } else {
    if (idx >= PB) return;
    int v = idx * 256 + threadIdx.x;
    if (v < N){
      int p = rowptr[v] + cnt[v];
      col[p++] = (u16)v;                   // self edge: dis[v]*xs[v] == dv^2*x[v]
      const int p1 = rowptr[v + 1];
      for (; p < p1; ++p) col[p] = (u16)N; // sentinel padding (xs[N]=0)
    }
    if (v == 0){
      int t = rowptr[N];
      for (int j = 0; j < 32; ++j) col[t + j] = (u16)N;
    }
  }
}

// ---------------- aggregation: XCD-sliced, 8 nodes x 8 lanes per wave (unchanged r15) ----------

#define GATHER8(p, c) \
  p##0 = ld((u32)(c)[0]); p##1 = ld((u32)(c)[1]); p##2 = ld((u32)(c)[2]); p##3 = ld((u32)(c)[3]); \
  p##4 = ld((u32)(c)[4]); p##5 = ld((u32)(c)[5]); p##6 = ld((u32)(c)[6]); p##7 = ld((u32)(c)[7]);

#define ACCQ(q) \
  a0 += bflo((q)[0]); a1 += bfhi((q)[0]); a2 += bflo((q)[1]); a3 += bfhi((q)[1]); \
  a4 += bflo((q)[2]); a5 += bfhi((q)[2]); a6 += bflo((q)[3]); a7 += bfhi((q)[3]);

#define CONS8(p) \
  ACCQ(p##0) ACCQ(p##1) ACCQ(p##2) ACCQ(p##3) ACCQ(p##4) ACCQ(p##5) ACCQ(p##6) ACCQ(p##7)

__global__ __launch_bounds__(256) void aggregate_kernel(const char* __restrict__ xsb,
                                                        const int* __restrict__ rowptr,
                                                        const u16* __restrict__ col,
                                                        const float* __restrict__ dis,
                                                        const int* __restrict__ perm,
                                                        char* __restrict__ ob, int N){
  const int f    = blockIdx.x & 7;                 // feature slice -> XCD
  const int widx = (blockIdx.x >> 3) * 4 + (threadIdx.x >> 6);
  const int lane = threadIdx.x & 63;
  const int g    = lane >> 3;                      // node group within wave
  const int pc   = lane & 7;                       // 16B piece within 128B slice
  const int idx  = widx * 8 + g;
  const u32 soff = (u32)((f << 7) + (pc << 4));

  int v, e0, mg;
  if (idx < N){ v = perm[idx]; e0 = rowptr[v]; mg = (rowptr[v + 1] - e0) >> 3; }
  else        { v = N;         e0 = rowptr[N]; mg = 1; }   // sentinel tail slots
  const u16* cp = col + e0;

  int M = mg;
  M = max(M, __shfl_xor(M, 8));
  M = max(M, __shfl_xor(M, 16));
  M = max(M, __shfl_xor(M, 32));

  auto ld = [&](u32 node) -> u32x4 {
    return *(const u32x4*)(xsb + (((size_t)node << 10) + soff));
  };
  auto ldc = [&](int k) -> u16x8 {
    u16x8 r;
    if (k < mg){
      r = *(const u16x8*)(cp + (k << 3));
    } else {
      #pragma unroll
      for (int j = 0; j < 8; ++j) r[j] = (u16)N;   // sentinel: zero row, adds 0
    }
    return r;
  };

  float a0=0.f,a1=0.f,a2=0.f,a3=0.f,a4=0.f,a5=0.f,a6=0.f,a7=0.f;

  u32x4 qa0, qa1, qa2, qa3, qa4, qa5, qa6, qa7;
  u32x4 qb0, qb1, qb2, qb3, qb4, qb5, qb6, qb7;

  u16x8 c0 = ldc(0);
  u16x8 c1 = ldc(1);
  GATHER8(qa, c0);

  int i = 1;
  for (; i + 1 < M; i += 2){
    c0 = ldc(i + 1);
    GATHER8(qb, c1);
    CONS8(qa);
    c1 = ldc(i + 2);
    GATHER8(qa, c0);
    CONS8(qb);
  }
  if (i < M){
    GATHER8(qb, c1);
    CONS8(qa);
    CONS8(qb);
  } else {
    CONS8(qa);
  }

  const float dv = dis[v];                          // dis[N] = 0 -> pad rows stay zero
  u32x4 r;
  r[0] = ((u32)f2bf(dv * a1) << 16) | f2bf(dv * a0);
  r[1] = ((u32)f2bf(dv * a3) << 16) | f2bf(dv * a2);
  r[2] = ((u32)f2bf(dv * a5) << 16) | f2bf(dv * a4);
  r[3] = ((u32)f2bf(dv * a7) << 16) | f2bf(dv * a6);
  *(u32x4*)(ob + (((size_t)v) << 10) + soff) = r;
}

// ---------------- GEMM: BM=128 x BN=512(full) x BK=32, 512 thr (unchanged from r12) ----------

__global__ __launch_bounds__(512) void gemm_kernel(const u16* __restrict__ A,
                                                   const u16* __restrict__ Bt,
                                                   const float* __restrict__ bias,
                                                   const float* __restrict__ dis,
                                                   u16* __restrict__ Cb,
                                                   float* __restrict__ Cf,
                                                   int n_real, int last){
  extern __shared__ u16 smem[];
  u16* const sAb = smem;            // [2][128*32] u16
  u16* const sBb = smem + 8192;     // [2][512*32] u16

  const int cpx = gridDim.x >> 3;
  const int wg  = (blockIdx.x & 7) * cpx + (blockIdx.x >> 3);
  const int bm0 = wg << 7;

  const int tid  = threadIdx.x;
  const int lane = tid & 63;
  const int wv   = tid >> 6;        // 0..7
  const int wm   = wv >> 2;         // 0..1 -> 64-row half
  const int wn   = wv & 3;          // 0..3 -> 128-col quarter
  const int lr   = lane & 15, lg = lane >> 4;

  f32x4 acc[4][8] = {};

  auto stage = [&](int bsel, int t){
    const int k0 = t << 5;
    u16* dA = sAb + (bsel << 12);
    u16* dB = sBb + (bsel << 14);
    {
      const int row = tid >> 2;
      const int gq  = ((tid & 3) ^ ((row >> 1) & 3)) << 3;   // pre-swizzled global chunk
      gload_lds16(A + (((size_t)(bm0 + row)) << 9) + k0 + gq,
                  (void*)&dA[(row << 5) + ((tid & 3) << 3)]); // linear dest
    }
    #pragma unroll
    for (int p = 0; p < 4; ++p){
      const int row = (tid >> 2) + (p << 7);
      const int gq  = ((tid & 3) ^ ((row >> 1) & 3)) << 3;
      gload_lds16(Bt + (((size_t)row) << 9) + k0 + gq,
                  (void*)&dB[(row << 5) + ((tid & 3) << 3)]);
    }
  };

  stage(0, 0);   // 5 loads/thread per stage
  stage(1, 1);   // 10 outstanding after prologue

  #pragma unroll
  for (int t = 0; t < 16; ++t){
    const int cur = t & 1;
    if (t < 15) asm volatile("s_waitcnt vmcnt(5)" ::: "memory");
    else        asm volatile("s_waitcnt vmcnt(0)" ::: "memory");
    __builtin_amdgcn_s_barrier();
    __builtin_amdgcn_sched_barrier(0);

    const bf16x8* A8 = (const bf16x8*)(sAb + (cur << 12));
    const bf16x8* B8 = (const bf16x8*)(sBb + (cur << 14));
    __builtin_amdgcn_s_setprio(1);
    bf16x8 af[4], bg[8];
    #pragma unroll
    for (int mi = 0; mi < 4; ++mi){
      const int row = (wm << 6) + (mi << 4) + lr;
      af[mi] = A8[(row << 2) + (lg ^ ((row >> 1) & 3))];     // read-side swizzle
    }
    #pragma unroll
    for (int ni = 0; ni < 8; ++ni){
      const int row = (wn << 7) + (ni << 4) + lr;
      bg[ni] = B8[(row << 2) + (lg ^ ((row >> 1) & 3))];
    }
    #pragma unroll
    for (int mi = 0; mi < 4; ++mi)
      #pragma unroll
      for (int ni = 0; ni < 8; ++ni)
        acc[mi][ni] = __builtin_amdgcn_mfma_f32_16x16x32_bf16(af[mi], bg[ni], acc[mi][ni], 0, 0, 0);
    __builtin_amdgcn_s_setprio(0);
    __builtin_amdgcn_sched_barrier(0);
    __builtin_amdgcn_s_barrier();      // all waves done reading buf[cur]
    if (t < 14) stage(cur, t + 2);     // refill freed buffer
  }

  float bb[8];
  #pragma unroll
  for (int ni = 0; ni < 8; ++ni) bb[ni] = bias[(wn << 7) + (ni << 4) + lr];

  // C/D layout: col=lane&15, row=(lane>>4)*4+reg  [m89-verified]
  #pragma unroll
  for (int mi = 0; mi < 4; ++mi){
    const int row0 = bm0 + (wm << 6) + (mi << 4) + (lg << 2);
    const f32x4 dv4 = *(const f32x4*)(dis + row0);   // dis padded; rows>=n_real unused
    #pragma unroll
    for (int ni = 0; ni < 8; ++ni){
      const int c0 = (wn << 7) + (ni << 4) + lr;
      #pragma unroll
      for (int r = 0; r < 4; ++r){
        const int row = row0 + r;
        const float val = fmaxf(acc[mi][ni][r] + bb[ni], 0.f);
        if (!last){
          Cb[(((size_t)row) << 9) + c0] = (row < n_real) ? f2bf(dv4[r] * val) : (u16)0;
        } else if (row < n_real){
          Cf[(((size_t)row) << 9) + c0] = val;
        }
      }
    }
  }
}

// ---------------- launch ----------------

extern "C" void kernel_launch(void* const* d_in, const int* in_sizes, int n_in,
                              void* d_out, int out_size, void* d_ws, size_t ws_size,
                              hipStream_t stream) {
  const float* x    = (const float*)d_in[0];
  const int*   ei   = (const int*)d_in[1];   // [2][E] int32: src = ei, dst = ei + E
  const float* W    = (const float*)d_in[2]; // [L][512][512]
  const float* bias = (const float*)d_in[3]; // [L][512]
  float* out = (float*)d_out;

  const int N = in_sizes[0] >> 9;       // 50000
  const int E = in_sizes[1] >> 1;       // 800000
  const int L = in_sizes[3] >> 9;       // 3
  const int MPAD = (N + 255) & ~255;    // 50176 (> N so row N is a zero pad row)
  const int NB = (N + 1023) / 1024;     // scan blocks (49)
  const int NBH = (N + 255) / 256;      // m-sort blocks (196)

  char* p = (char*)d_ws;
  auto alloc = [&](size_t bytes){ char* q = p; p += (bytes + 255) & ~(size_t)255; return q; };
  u16*   xb       = (u16*)alloc((size_t)MPAD * 512 * 2);
  u16*   aggb     = (u16*)alloc((size_t)MPAD * 512 * 2);
  u16*   wt       = (u16*)alloc((size_t)L * 512 * 512 * 2);
  float* dis      = (float*)alloc((size_t)(MPAD + 4) * 4);  // padded for epilogue f32x4 reads
  int*   rowptr_d = (int*)alloc((size_t)(N + 1) * 4);
  int*   cursor_d = (int*)alloc((size_t)N * 4);
  int*   cnt_d    = (int*)alloc((size_t)N * 4);
  int*   perm     = (int*)alloc((size_t)N * 4);
  int*   bh       = (int*)alloc((size_t)32 * NBH * 4);
  u16*   col      = (u16*)alloc(((size_t)E + 9 * (size_t)N + 64) * 2);  // +self edges +padding
  int*   bsums_d  = (int*)alloc(256 * 4);

  hipFuncSetAttribute((const void*)gemm_kernel,
                      hipFuncAttributeMaxDynamicSharedMemorySize, 81920);

  hipMemsetAsync(cnt_d, 0, (size_t)N * 4, stream);
  hipMemsetAsync(aggb + (size_t)N * 512, 0, (size_t)(MPAD - N) * 512 * 2, stream);

  // P1: count_deg (vec4) || convert_w (transpose tiles)
  const int CB = (E / 4 + 255) / 256;     // 782
  prep1_kernel<<<CB + L * 64, 256, 0, stream>>>(ei + E, E, CB, cnt_d, W, wt);

  scan1_kernel<<<NB, 1024, 0, stream>>>(cnt_d, N, rowptr_d, bsums_d);
  scan2_kernel<<<1, 256, 0, stream>>>(bsums_d, NB);
  finalize_kernel<<<(N + 255) / 256, 256, 0, stream>>>(rowptr_d, cursor_d, bsums_d, NB, cnt_d, dis, N);

  // m-sort (perf-only node permutation for divergence-free 8-node waves)
  mhist_kernel<<<NBH, 256, 0, stream>>>(cnt_d, N, NBH, bh);
  mscan_kernel<<<1, 1024, 0, stream>>>(bh, 32 * NBH);
  mscatter_kernel<<<NBH, 256, 0, stream>>>(cnt_d, N, NBH, bh, perm);

  // P3: convert_x || fill_csr || pad_fill, interleaved 4:1 across the grid
  const int ntot = MPAD * 512;
  const int XB = (ntot / 8 + 255) / 256;  // 12544
  const int FB = (E + 255) / 256;         // 3125
  const int PB = (N + 255) / 256;         // 196
  const int G3 = ((XB + FB + PB + 4) / 5) * 5;   // grid multiple of 5; guards absorb slack
  prep3_kernel<<<G3, 256, 0, stream>>>(x, dis, (u32*)xb, N * 512, ntot, XB,
                                       ei, ei + E, E, FB, PB,
                                       cursor_d, rowptr_d, cnt_d, N, col);

  const int ggrid = MPAD / 128;           // 392 = 8*49, divisible by 8
  const int agrid = ((N + 31) / 32) * 8;  // 32 nodes/block x 8 slices
  for (int l = 0; l < L; ++l){
    aggregate_kernel<<<agrid, 256, 0, stream>>>((const char*)xb, rowptr_d, col, dis,
                                                perm, (char*)aggb, N);
    gemm_kernel<<<ggrid, 512, 81920, stream>>>(aggb, wt + (size_t)l * 512 * 512,
                                               bias + (size_t)l * 512, dis,
                                               xb, out, N, (l == L - 1) ? 1 : 0);
  }
}